// Round 2
// baseline (660.918 us; speedup 1.0000x reference)
//
#include <hip/hip_runtime.h>
#include <hip/hip_bf16.h>

#define BR_N     1000000
#define DIM      128
#define TILE_M   64
#define NTILES   (BR_N / TILE_M)   /* 15625, exact */
#define NTHREADS 512
#define NBLOCKS  1024

typedef __attribute__((ext_vector_type(8))) short    bf16x8;
typedef __attribute__((ext_vector_type(4))) float    f32x4;
typedef __attribute__((ext_vector_type(4))) unsigned u32x4;

// f32 pair -> packed bf16x2 (RNE) via v_cvt_pk_bf16_f32
static __device__ __forceinline__ unsigned pk2(float a, float b) {
    union { __hip_bfloat162 h; unsigned u; } v;
    v.h = __float22bfloat162_rn(float2{a, b});
    return v.u;
}

union FragU { bf16x8 v; u32x4 u; };

static __device__ __forceinline__ bf16x8 cvt8(const f32x4 a, const f32x4 b) {
    FragU r;
    r.u.x = pk2(a.x, a.y);
    r.u.y = pk2(a.z, a.w);
    r.u.z = pk2(b.x, b.y);
    r.u.w = pk2(b.z, b.w);
    return r.v;
}

static __device__ __forceinline__ float bf2f(unsigned short b) {
    union { unsigned u; float f; } v;
    v.u = ((unsigned)b) << 16;
    return v.f;
}

// out = sigmoid(s@Vs.T + o@Vo.T) * relu(s@Ws.T + o@Wo.T + s*(o.w))
__global__ __launch_bounds__(NTHREADS, 4)
void relup_kernel(const float* __restrict__ S, const float* __restrict__ O,
                  const float* __restrict__ Vs, const float* __restrict__ Vo,
                  const float* __restrict__ Ws, const float* __restrict__ Wo,
                  const float* __restrict__ W1, float* __restrict__ out)
{
    // bf16 tiles, row stride 256 B, byte-swizzled: 16B granule g of row r lives at (g ^ (r&7))
    __shared__ __align__(16) unsigned char sT[TILE_M * 256];
    __shared__ __align__(16) unsigned char oT[TILE_M * 256];
    __shared__ float dotv[TILE_M];

    const int tid  = threadIdx.x;
    const int lane = tid & 63;
    const int wv   = tid >> 6;       // wave id 0..7, owns output cols [wv*16, wv*16+16)
    const int c0   = wv << 4;

    // ---- preload weight B-fragments into registers (held for whole kernel) ----
    // B = W.T, so B-frag(kk): lane holds W[c0+(lane&15)][kk*32 + (lane>>4)*8 + j], 8 contiguous floats
    bf16x8 fVs[4], fVo[4], fWs[4], fWo[4];
    {
        const int wr = c0 + (lane & 15);
        const int wc = (lane >> 4) << 3;
        #pragma unroll
        for (int kk = 0; kk < 4; ++kk) {
            const int off = wr * DIM + kk * 32 + wc;
            fVs[kk] = cvt8(*(const f32x4*)(Vs + off), *(const f32x4*)(Vs + off + 4));
            fVo[kk] = cvt8(*(const f32x4*)(Vo + off), *(const f32x4*)(Vo + off + 4));
            fWs[kk] = cvt8(*(const f32x4*)(Ws + off), *(const f32x4*)(Ws + off + 4));
            fWo[kk] = cvt8(*(const f32x4*)(Wo + off), *(const f32x4*)(Wo + off + 4));
        }
    }

    // staging assignment: thread -> (row 0..63, 16-float segment 0..7)
    const int str = tid >> 3;
    const int seg = tid & 7;
    const int swS = (str & 7) << 4;
    const int sb0 = str * 256 + ((seg * 32) ^ swS);
    const int sb1 = str * 256 + (((seg * 32) + 16) ^ swS);

    // w segment held in registers (loop-invariant)
    const float* wp = W1 + seg * 16;
    const f32x4 wr0 = ((const f32x4*)wp)[0], wr1 = ((const f32x4*)wp)[1];
    const f32x4 wr2 = ((const f32x4*)wp)[2], wr3 = ((const f32x4*)wp)[3];

    int t = blockIdx.x;

    // ---- prefetch first tile into registers ----
    f32x4 Ps0, Ps1, Ps2, Ps3, Po0, Po1, Po2, Po3;
    {
        const float* sp = S + (t * TILE_M + str) * DIM + seg * 16;
        const float* op = O + (t * TILE_M + str) * DIM + seg * 16;
        Ps0 = ((const f32x4*)sp)[0]; Ps1 = ((const f32x4*)sp)[1];
        Ps2 = ((const f32x4*)sp)[2]; Ps3 = ((const f32x4*)sp)[3];
        Po0 = ((const f32x4*)op)[0]; Po1 = ((const f32x4*)op)[1];
        Po2 = ((const f32x4*)op)[2]; Po3 = ((const f32x4*)op)[3];
    }

    while (t < NTILES) {
        const int row0 = t * TILE_M;
        const int tn   = t + (int)gridDim.x;
        const int tp   = (tn < NTILES) ? tn : t;   // clamp: harmless L2-hot reload on last iter

        // ---- PHASE A: dot(o,w) + pack prefetched regs -> LDS (swizzled) ----
        {
            float p = Po0.x*wr0.x + Po0.y*wr0.y + Po0.z*wr0.z + Po0.w*wr0.w
                    + Po1.x*wr1.x + Po1.y*wr1.y + Po1.z*wr1.z + Po1.w*wr1.w
                    + Po2.x*wr2.x + Po2.y*wr2.y + Po2.z*wr2.z + Po2.w*wr2.w
                    + Po3.x*wr3.x + Po3.y*wr3.y + Po3.z*wr3.z + Po3.w*wr3.w;

            u32x4 pa = { pk2(Ps0.x,Ps0.y), pk2(Ps0.z,Ps0.w), pk2(Ps1.x,Ps1.y), pk2(Ps1.z,Ps1.w) };
            u32x4 pb = { pk2(Ps2.x,Ps2.y), pk2(Ps2.z,Ps2.w), pk2(Ps3.x,Ps3.y), pk2(Ps3.z,Ps3.w) };
            u32x4 pc = { pk2(Po0.x,Po0.y), pk2(Po0.z,Po0.w), pk2(Po1.x,Po1.y), pk2(Po1.z,Po1.w) };
            u32x4 pd = { pk2(Po2.x,Po2.y), pk2(Po2.z,Po2.w), pk2(Po3.x,Po3.y), pk2(Po3.z,Po3.w) };
            *(u32x4*)(sT + sb0) = pa;
            *(u32x4*)(sT + sb1) = pb;
            *(u32x4*)(oT + sb0) = pc;
            *(u32x4*)(oT + sb1) = pd;

            p += __shfl_xor(p, 1);
            p += __shfl_xor(p, 2);
            p += __shfl_xor(p, 4);
            if (seg == 0) dotv[str] = p;
        }
        __syncthreads();

        // ---- PHASE B: issue next tile's loads (latency hides under phase C) ----
        {
            const float* sp = S + (tp * TILE_M + str) * DIM + seg * 16;
            const float* op = O + (tp * TILE_M + str) * DIM + seg * 16;
            Ps0 = ((const f32x4*)sp)[0]; Ps1 = ((const f32x4*)sp)[1];
            Ps2 = ((const f32x4*)sp)[2]; Ps3 = ((const f32x4*)sp)[3];
            Po0 = ((const f32x4*)op)[0]; Po1 = ((const f32x4*)op)[1];
            Po2 = ((const f32x4*)op)[2]; Po3 = ((const f32x4*)op)[3];
        }

        // ---- PHASE C: MFMA + epilogue (all from LDS) ----
        #pragma unroll
        for (int b = 0; b < 4; ++b) {
            const int r0  = b << 4;
            const int ar  = r0 + (lane & 15);
            const int swA = (ar & 7) << 4;
            const int acb = (lane >> 4) << 4;     // byte offset of this lane's 8 bf16 within a 64B k-step
            bf16x8 fs[4], fo[4];
            #pragma unroll
            for (int kk = 0; kk < 4; ++kk) {
                const int cb = ((kk << 6) + acb) ^ swA;
                fs[kk] = *(const bf16x8*)(sT + ar * 256 + cb);
                fo[kk] = *(const bf16x8*)(oT + ar * 256 + cb);
            }
            f32x4 accg = {0.f, 0.f, 0.f, 0.f};
            f32x4 accd = {0.f, 0.f, 0.f, 0.f};
            #pragma unroll
            for (int kk = 0; kk < 4; ++kk) {
                accg = __builtin_amdgcn_mfma_f32_16x16x32_bf16(fs[kk], fVs[kk], accg, 0, 0, 0);
                accg = __builtin_amdgcn_mfma_f32_16x16x32_bf16(fo[kk], fVo[kk], accg, 0, 0, 0);
                accd = __builtin_amdgcn_mfma_f32_16x16x32_bf16(fs[kk], fWs[kk], accd, 0, 0, 0);
                accd = __builtin_amdgcn_mfma_f32_16x16x32_bf16(fo[kk], fWo[kk], accd, 0, 0, 0);
            }
            // epilogue: C/D layout (measured): lane reg r -> row (lane>>4)*4+r, col lane&15
            const int col = c0 + (lane & 15);
            #pragma unroll
            for (int r = 0; r < 4; ++r) {
                const int row = r0 + ((lane >> 4) << 2) + r;
                const int gi  = (row0 + row) * DIM + col;
                // s (bf16) from the staged LDS tile — no global re-read
                const int sOff = row * 256 + (((col * 2)) ^ ((row & 7) << 4));
                const float sval  = bf2f(*(const unsigned short*)(sT + sOff));
                const float inter = sval * dotv[row];
                const float gate  = 1.0f / (1.0f + __expf(-accg[r]));
                float dir = accd[r] + inter;
                dir = dir > 0.0f ? dir : 0.0f;
                __builtin_nontemporal_store(gate * dir, &out[gi]);
            }
        }
        __syncthreads();
        t = tn;
    }
}

extern "C" void kernel_launch(void* const* d_in, const int* in_sizes, int n_in,
                              void* d_out, int out_size, void* d_ws, size_t ws_size,
                              hipStream_t stream) {
    const float* S  = (const float*)d_in[0];
    const float* O  = (const float*)d_in[1];
    const float* Vs = (const float*)d_in[2];
    const float* Vo = (const float*)d_in[3];
    const float* Ws = (const float*)d_in[4];
    const float* Wo = (const float*)d_in[5];
    const float* w  = (const float*)d_in[6];
    float* out = (float*)d_out;
    relup_kernel<<<NBLOCKS, NTHREADS, 0, stream>>>(S, O, Vs, Vo, Ws, Wo, w, out);
}

// Round 3
// 320.773 us; speedup vs baseline: 2.0604x; 2.0604x over previous
//
#include <hip/hip_runtime.h>
#include <hip/hip_bf16.h>

#define BR_N     1000000
#define DIM      128
#define TILE_M   64
#define NTILES   (BR_N / TILE_M)   /* 15625, exact */
#define NTHREADS 512
#define NBLOCKS  1024

typedef __attribute__((ext_vector_type(8))) short    bf16x8;
typedef __attribute__((ext_vector_type(4))) float    f32x4;
typedef __attribute__((ext_vector_type(4))) unsigned u32x4;

// f32 pair -> packed bf16x2 (RNE) via v_cvt_pk_bf16_f32
static __device__ __forceinline__ unsigned pk2(float a, float b) {
    union { __hip_bfloat162 h; unsigned u; } v;
    v.h = __float22bfloat162_rn(float2{a, b});
    return v.u;
}

union FragU { bf16x8 v; u32x4 u; };

static __device__ __forceinline__ bf16x8 cvt8(const f32x4 a, const f32x4 b) {
    FragU r;
    r.u.x = pk2(a.x, a.y);
    r.u.y = pk2(a.z, a.w);
    r.u.z = pk2(b.x, b.y);
    r.u.w = pk2(b.z, b.w);
    return r.v;
}

static __device__ __forceinline__ float bf2f(unsigned short b) {
    union { unsigned u; float f; } v;
    v.u = ((unsigned)b) << 16;
    return v.f;
}

// out = sigmoid(s@Vs.T + o@Vo.T) * relu(s@Ws.T + o@Wo.T + s*(o.w))
// launch_bounds(512,2): VGPR cap 128 — weights(64) + prefetch(32) + working fits
// WITHOUT scratch spill. (512,4) capped at 64 and spilled the weight frags ->
// +1.25 GB HBM fetch (R2 post-mortem).
__global__ __launch_bounds__(NTHREADS, 2)
void relup_kernel(const float* __restrict__ S, const float* __restrict__ O,
                  const float* __restrict__ Vs, const float* __restrict__ Vo,
                  const float* __restrict__ Ws, const float* __restrict__ Wo,
                  const float* __restrict__ W1, float* __restrict__ out)
{
    // bf16 tiles, row stride 256 B, byte-swizzled: 16B granule g of row r lives at (g ^ (r&7))
    __shared__ __align__(16) unsigned char sT[TILE_M * 256];
    __shared__ __align__(16) unsigned char oT[TILE_M * 256];
    __shared__ float dotv[TILE_M];

    const int tid  = threadIdx.x;
    const int lane = tid & 63;
    const int wv   = tid >> 6;       // wave id 0..7, owns output cols [wv*16, wv*16+16)
    const int c0   = wv << 4;

    // ---- preload weight B-fragments into registers (held for whole kernel) ----
    // B = W.T, so B-frag(kk): lane holds W[c0+(lane&15)][kk*32 + (lane>>4)*8 + j], 8 contiguous floats
    bf16x8 fVs[4], fVo[4], fWs[4], fWo[4];
    {
        const int wr = c0 + (lane & 15);
        const int wc = (lane >> 4) << 3;
        #pragma unroll
        for (int kk = 0; kk < 4; ++kk) {
            const int off = wr * DIM + kk * 32 + wc;
            fVs[kk] = cvt8(*(const f32x4*)(Vs + off), *(const f32x4*)(Vs + off + 4));
            fVo[kk] = cvt8(*(const f32x4*)(Vo + off), *(const f32x4*)(Vo + off + 4));
            fWs[kk] = cvt8(*(const f32x4*)(Ws + off), *(const f32x4*)(Ws + off + 4));
            fWo[kk] = cvt8(*(const f32x4*)(Wo + off), *(const f32x4*)(Wo + off + 4));
        }
    }

    // staging assignment: thread -> (row 0..63, 16-float segment 0..7)
    const int str = tid >> 3;
    const int seg = tid & 7;
    const int swS = (str & 7) << 4;
    const int sb0 = str * 256 + ((seg * 32) ^ swS);
    const int sb1 = str * 256 + (((seg * 32) + 16) ^ swS);
    const float* wp = W1 + seg * 16;   // reloaded per tile (L2-hot) to save 16 VGPRs

    int t = blockIdx.x;

    // ---- prefetch first tile into registers ----
    f32x4 Ps0, Ps1, Ps2, Ps3, Po0, Po1, Po2, Po3;
    {
        const float* sp = S + (t * TILE_M + str) * DIM + seg * 16;
        const float* op = O + (t * TILE_M + str) * DIM + seg * 16;
        Ps0 = ((const f32x4*)sp)[0]; Ps1 = ((const f32x4*)sp)[1];
        Ps2 = ((const f32x4*)sp)[2]; Ps3 = ((const f32x4*)sp)[3];
        Po0 = ((const f32x4*)op)[0]; Po1 = ((const f32x4*)op)[1];
        Po2 = ((const f32x4*)op)[2]; Po3 = ((const f32x4*)op)[3];
    }

    while (t < NTILES) {
        const int row0 = t * TILE_M;
        const int tn   = t + (int)gridDim.x;
        const int tp   = (tn < NTILES) ? tn : t;   // clamp: harmless L2-hot reload on last iter

        // ---- PHASE A: dot(o,w) + pack current regs -> LDS; then issue next loads ----
        {
            const f32x4 w0 = ((const f32x4*)wp)[0], w1 = ((const f32x4*)wp)[1];
            const f32x4 w2 = ((const f32x4*)wp)[2], w3 = ((const f32x4*)wp)[3];
            float p = Po0.x*w0.x + Po0.y*w0.y + Po0.z*w0.z + Po0.w*w0.w
                    + Po1.x*w1.x + Po1.y*w1.y + Po1.z*w1.z + Po1.w*w1.w
                    + Po2.x*w2.x + Po2.y*w2.y + Po2.z*w2.z + Po2.w*w2.w
                    + Po3.x*w3.x + Po3.y*w3.y + Po3.z*w3.z + Po3.w*w3.w;

            u32x4 pa = { pk2(Ps0.x,Ps0.y), pk2(Ps0.z,Ps0.w), pk2(Ps1.x,Ps1.y), pk2(Ps1.z,Ps1.w) };
            u32x4 pb = { pk2(Ps2.x,Ps2.y), pk2(Ps2.z,Ps2.w), pk2(Ps3.x,Ps3.y), pk2(Ps3.z,Ps3.w) };
            u32x4 pc = { pk2(Po0.x,Po0.y), pk2(Po0.z,Po0.w), pk2(Po1.x,Po1.y), pk2(Po1.z,Po1.w) };
            u32x4 pd = { pk2(Po2.x,Po2.y), pk2(Po2.z,Po2.w), pk2(Po3.x,Po3.y), pk2(Po3.z,Po3.w) };
            *(u32x4*)(sT + sb0) = pa;
            *(u32x4*)(sT + sb1) = pb;
            *(u32x4*)(oT + sb0) = pc;
            *(u32x4*)(oT + sb1) = pd;

            // issue next tile's loads NOW — last read of Ps/Po was the pack above;
            // latency hides under shfl + barrier + MFMA phase
            {
                const float* sp = S + (tp * TILE_M + str) * DIM + seg * 16;
                const float* op = O + (tp * TILE_M + str) * DIM + seg * 16;
                Ps0 = ((const f32x4*)sp)[0]; Ps1 = ((const f32x4*)sp)[1];
                Ps2 = ((const f32x4*)sp)[2]; Ps3 = ((const f32x4*)sp)[3];
                Po0 = ((const f32x4*)op)[0]; Po1 = ((const f32x4*)op)[1];
                Po2 = ((const f32x4*)op)[2]; Po3 = ((const f32x4*)op)[3];
            }

            p += __shfl_xor(p, 1);
            p += __shfl_xor(p, 2);
            p += __shfl_xor(p, 4);
            if (seg == 0) dotv[str] = p;
        }
        __syncthreads();

        // ---- PHASE B: MFMA + epilogue (all from LDS) ----
        #pragma unroll
        for (int b = 0; b < 4; ++b) {
            const int r0  = b << 4;
            const int ar  = r0 + (lane & 15);
            const int swA = (ar & 7) << 4;
            const int acb = (lane >> 4) << 4;     // byte offset of this lane's 8 bf16 within a 64B k-step
            bf16x8 fs[4], fo[4];
            #pragma unroll
            for (int kk = 0; kk < 4; ++kk) {
                const int cb = ((kk << 6) + acb) ^ swA;
                fs[kk] = *(const bf16x8*)(sT + ar * 256 + cb);
                fo[kk] = *(const bf16x8*)(oT + ar * 256 + cb);
            }
            f32x4 accg = {0.f, 0.f, 0.f, 0.f};
            f32x4 accd = {0.f, 0.f, 0.f, 0.f};
            #pragma unroll
            for (int kk = 0; kk < 4; ++kk) {
                accg = __builtin_amdgcn_mfma_f32_16x16x32_bf16(fs[kk], fVs[kk], accg, 0, 0, 0);
                accg = __builtin_amdgcn_mfma_f32_16x16x32_bf16(fo[kk], fVo[kk], accg, 0, 0, 0);
                accd = __builtin_amdgcn_mfma_f32_16x16x32_bf16(fs[kk], fWs[kk], accd, 0, 0, 0);
                accd = __builtin_amdgcn_mfma_f32_16x16x32_bf16(fo[kk], fWo[kk], accd, 0, 0, 0);
            }
            // epilogue: C/D layout (measured): lane reg r -> row (lane>>4)*4+r, col lane&15
            const int col = c0 + (lane & 15);
            #pragma unroll
            for (int r = 0; r < 4; ++r) {
                const int row = r0 + ((lane >> 4) << 2) + r;
                const int gi  = (row0 + row) * DIM + col;
                // s (bf16) from the staged LDS tile — no global re-read
                const int sOff = row * 256 + ((col * 2) ^ ((row & 7) << 4));
                const float sval  = bf2f(*(const unsigned short*)(sT + sOff));
                const float inter = sval * dotv[row];
                const float gate  = 1.0f / (1.0f + __expf(-accg[r]));
                float dir = accd[r] + inter;
                dir = dir > 0.0f ? dir : 0.0f;
                out[gi] = gate * dir;
            }
        }
        __syncthreads();
        t = tn;
    }
}

extern "C" void kernel_launch(void* const* d_in, const int* in_sizes, int n_in,
                              void* d_out, int out_size, void* d_ws, size_t ws_size,
                              hipStream_t stream) {
    const float* S  = (const float*)d_in[0];
    const float* O  = (const float*)d_in[1];
    const float* Vs = (const float*)d_in[2];
    const float* Vo = (const float*)d_in[3];
    const float* Ws = (const float*)d_in[4];
    const float* Wo = (const float*)d_in[5];
    const float* w  = (const float*)d_in[6];
    float* out = (float*)d_out;
    relup_kernel<<<NBLOCKS, NTHREADS, 0, stream>>>(S, O, Vs, Vo, Ws, Wo, w, out);
}